// Round 9
// baseline (50.808 us; speedup 1.0000x reference)
//
#include <hip/hip_runtime.h>
#include <stdint.h>

// Problem geometry (fixed by the reference file).
constexpr int DIM  = 256;
constexpr int SEQ  = 4096;
constexpr int D4   = DIM / 4;            // 64 float4 per token
constexpr int SROW = SEQ * D4;           // float4 per sequence (262144)

// Native vector type: __builtin_nontemporal_* requires a real vector.
typedef float f32x4 __attribute__((ext_vector_type(4)));

// ---------------------------------------------------------------------------
// Single fused kernel.
//
// Inline mask-dtype detection (see R6 notes): prefix-valid masks mean any
// padding puts a 1 in some row's LAST byte (flat offset == 3 mod 4); int32
// {0,1} words have zero upper bytes there. any-nonzero -> bool layout;
// all-zero -> int32 path (also correct for bool-no-padding: all words zero
// => all-valid either way). In-bounds under both layouts.
//
// R8->R9 single change: break the mask->pe ADDRESS dependency. Always load
// pe[i & (SROW-1)] (address independent of the mask, issues immediately)
// and select the VALUE against the row-0 fallback pe[d4] (held in regs,
// loaded once per thread, wave-coalesced L2 hit). The scalar mask load,
// the pe gather, and the x load now all issue in parallel; the mask only
// feeds a v_cndmask. HBM bytes unchanged -> final latency-structure test.
// ---------------------------------------------------------------------------
__global__ __launch_bounds__(256) void pe_add_kernel(
        const f32x4*    __restrict__ x,
        const uint8_t*  __restrict__ mask_b,
        const uint32_t* __restrict__ mask_w,
        const f32x4*    __restrict__ pe,
        f32x4*          __restrict__ out,
        int nrows,
        int total4) {
    // --- inline layout detection (wave-uniform) ---
    const int r = (int)(threadIdx.x & 31) % (nrows > 0 ? nrows : 1);
    const bool isbool = __any(mask_b[r * SEQ + (SEQ - 1)] != 0);

    const int i0 = blockIdx.x * 512 + threadIdx.x;
    const int i1 = i0 + 256;
    const int d4 = i0 & (D4 - 1);              // same for i1 (256 % 64 == 0)

    // Row-0 fallback value (pad tokens gather pe[0]); L2-hit, once/thread.
    const f32x4 pe0 = pe[d4];

    if (i1 < total4) {
        // Unconditional pe row loads — address has NO mask dependency.
        const f32x4 pv0 = pe[i0 & (SROW - 1)];
        const f32x4 pv1 = pe[i1 & (SROW - 1)];

        // Wave-uniform token indices; scalar-path mask fetch (in parallel
        // with the vector loads above).
        const int t0 = __builtin_amdgcn_readfirstlane(i0 >> 6);
        const int t1 = t0 + 4;                 // i1 = i0 + 256 -> +4 tokens
        uint32_t m0, m1;
        if (isbool) {
            const uint32_t w0 = mask_w[t0 >> 2];
            const uint32_t w1 = mask_w[t1 >> 2];
            m0 = (w0 >> ((t0 & 3) * 8)) & 0xFFu;
            m1 = (w1 >> ((t1 & 3) * 8)) & 0xFFu;
        } else {
            m0 = mask_w[t0];
            m1 = mask_w[t1];
        }

        const f32x4 xv0 = __builtin_nontemporal_load(&x[i0]);
        const f32x4 xv1 = __builtin_nontemporal_load(&x[i1]);

        // Value select (wave-uniform condition -> cheap either way).
        const f32x4 a0 = (m0 == 0) ? pv0 : pe0;
        const f32x4 a1 = (m1 == 0) ? pv1 : pe0;

        out[i0] = xv0 + a0;
        out[i1] = xv1 + a1;
    } else if (i0 < total4) {
        // Generic tail (never taken at this problem size).
        const int t0 = i0 >> 6;
        const int m0 = isbool ? (int)mask_b[t0] : (int)mask_w[t0];
        const f32x4 xv0 = __builtin_nontemporal_load(&x[i0]);
        const f32x4 pv0 = pe[i0 & (SROW - 1)];
        out[i0] = xv0 + ((m0 == 0) ? pv0 : pe0);
    }
}

extern "C" void kernel_launch(void* const* d_in, const int* in_sizes, int n_in,
                              void* d_out, int out_size, void* d_ws, size_t ws_size,
                              hipStream_t stream) {
    const f32x4*  x    = (const f32x4*)d_in[0];
    const void*   mask = d_in[1];
    const f32x4*  pe   = (const f32x4*)d_in[2];
    f32x4*        out  = (f32x4*)d_out;

    const int mask_elems = in_sizes[1];        // B*S
    const int nrows      = mask_elems / SEQ;   // B
    const int total4     = out_size / 4;       // B*S*DIM/4 = 8,388,608

    const int grid = (total4 + 511) / 512;     // 16384 exact
    pe_add_kernel<<<grid, 256, 0, stream>>>(
        x, (const uint8_t*)mask, (const uint32_t*)mask, pe, out, nrows, total4);
}

// Round 10
// 47.473 us; speedup vs baseline: 1.0703x; 1.0703x over previous
//
#include <hip/hip_runtime.h>
#include <stdint.h>

// Problem geometry (fixed by the reference file).
constexpr int DIM  = 256;
constexpr int SEQ  = 4096;
constexpr int D4   = DIM / 4;            // 64 float4 per token
constexpr int SROW = SEQ * D4;           // float4 per sequence (262144)

// Native vector type: __builtin_nontemporal_* requires a real vector.
typedef float f32x4 __attribute__((ext_vector_type(4)));

// ---------------------------------------------------------------------------
// Single fused kernel — REVERT to R8 (best: 48.13 us).
// R9's value-select variant (extra pe0 vmem load to break the mask->pe
// address chain) regressed to 50.8 us: at full occupancy the scalar-load
// latency is TLP-hidden, so extra vmem issue only costs. Keep R8.
//
// Inline mask-dtype detection: prefix-valid masks mean any padding puts a
// 1 in some row's LAST byte (flat offset == 3 mod 4); int32 {0,1} words
// have zero upper bytes there. any-nonzero -> bool layout; all-zero ->
// int32 path (also correct for bool-no-padding: all words zero => all
// valid either way). In-bounds under both layouts.
//
// Main body: out[i] = x[i] + pe4[ valid ? i mod (SEQ*D4) : i mod D4 ]
// (pos == s for valid tokens under prefix masks, 0 for padding).
// Two float4 per thread at base and base+256: contiguous 1 KB wave
// segments. Wave-uniform mask fetch through the SCALAR path (each wave's
// 64 lanes cover exactly one token). nt load on x (zero reuse; keeps the
// 4 MiB pe table L2-resident); normal write-back store.
// ---------------------------------------------------------------------------
__global__ __launch_bounds__(256) void pe_add_kernel(
        const f32x4*    __restrict__ x,
        const uint8_t*  __restrict__ mask_b,
        const uint32_t* __restrict__ mask_w,
        const f32x4*    __restrict__ pe,
        f32x4*          __restrict__ out,
        int nrows,
        int total4) {
    // --- inline layout detection (wave-uniform) ---
    const int r = (int)(threadIdx.x & 31) % (nrows > 0 ? nrows : 1);
    const bool isbool = __any(mask_b[r * SEQ + (SEQ - 1)] != 0);

    const int i0 = blockIdx.x * 512 + threadIdx.x;
    const int i1 = i0 + 256;

    if (i1 < total4) {
        // Wave-uniform token indices (64 consecutive i per wave = 1 token).
        const int t0 = __builtin_amdgcn_readfirstlane(i0 >> 6);
        const int t1 = t0 + 4;                     // i1 = i0 + 256 -> +4 tokens

        // Scalar-path mask fetch (uniform u32 loads, both layouts).
        uint32_t m0, m1;
        if (isbool) {
            const uint32_t w0 = mask_w[t0 >> 2];
            const uint32_t w1 = mask_w[t1 >> 2];
            m0 = (w0 >> ((t0 & 3) * 8)) & 0xFFu;
            m1 = (w1 >> ((t1 & 3) * 8)) & 0xFFu;
        } else {
            m0 = mask_w[t0];
            m1 = mask_w[t1];
        }

        // pe row base (wave-uniform scalar), + per-lane d4.
        const int d4  = i0 & (D4 - 1);             // same for i1 (256 % 64 == 0)
        const int rb0 = (m0 == 0) ? ((t0 & (SEQ - 1)) << 6) : 0;
        const int rb1 = (m1 == 0) ? ((t1 & (SEQ - 1)) << 6) : 0;

        const f32x4 xv0 = __builtin_nontemporal_load(&x[i0]);
        const f32x4 xv1 = __builtin_nontemporal_load(&x[i1]);
        out[i0] = xv0 + pe[rb0 + d4];
        out[i1] = xv1 + pe[rb1 + d4];
    } else if (i0 < total4) {
        // Generic tail (never taken at this problem size).
        const int t0 = i0 >> 6;
        const int m0 = isbool ? (int)mask_b[t0] : (int)mask_w[t0];
        const f32x4 xv0 = __builtin_nontemporal_load(&x[i0]);
        const int p0 = (m0 == 0) ? (i0 & (SROW - 1)) : (i0 & (D4 - 1));
        out[i0] = xv0 + pe[p0];
    }
}

extern "C" void kernel_launch(void* const* d_in, const int* in_sizes, int n_in,
                              void* d_out, int out_size, void* d_ws, size_t ws_size,
                              hipStream_t stream) {
    const f32x4*  x    = (const f32x4*)d_in[0];
    const void*   mask = d_in[1];
    const f32x4*  pe   = (const f32x4*)d_in[2];
    f32x4*        out  = (f32x4*)d_out;

    const int mask_elems = in_sizes[1];        // B*S
    const int nrows      = mask_elems / SEQ;   // B
    const int total4     = out_size / 4;       // B*S*DIM/4 = 8,388,608

    const int grid = (total4 + 511) / 512;     // 16384 exact
    pe_add_kernel<<<grid, 256, 0, stream>>>(
        x, (const uint8_t*)mask, (const uint32_t*)mask, pe, out, nrows, total4);
}